// Round 4
// baseline (919.141 us; speedup 1.0000x reference)
//
#include <hip/hip_runtime.h>
#include <hip/hip_cooperative_groups.h>
#include <math.h>

namespace cg = cooperative_groups;

#define N_NODES 40000
#define N_EDGES 640000
#define IN_CH 128
#define HID_CH 256
#define EDGE_DIM 64
#define N_SAMP 2048
#define NSEL (1 + 2 * N_SAMP) /* 4097 selected rows */
#define MAXU 4097
#define GRID 512 /* 2 blocks/CU; LDS 49.9KB allows 3/CU so co-residency is safe */
#define BLK 256

struct EdgeSmem { // 49920 B
    float sWe[EDGE_DIM * IN_CH];   // 32 KB
    float sAttr[4][16 * EDGE_DIM]; // 16 KB
    int sE[4][16], sS[4][16], sL[4][16];
};
struct MlpSmem { // 24704 B
    float sin_[16][IN_CH];
    float shid[16][HID_CH];
    int snode[16], sslot[16];
};
struct CmpSmem { int woff[4]; int bbase; };
struct ScSmem { float wsum[4]; };

__global__ __launch_bounds__(BLK) void mega_kernel(
    const float* __restrict__ x, const int* __restrict__ ei,
    const float* __restrict__ edge_attr,
    const int* __restrict__ pos, const int* __restrict__ neg,
    const float* __restrict__ We, const float* __restrict__ be,
    const float* __restrict__ W1, const float* __restrict__ b1,
    const float* __restrict__ W2, const float* __restrict__ b2,
    const float* __restrict__ thrn,
    int* slot, int* counters, int4* cmp, float* agg_c,
    float* emb, float* partial, float* out)
{
    cg::grid_group grid = cg::this_grid();
    __shared__ __align__(16) char smem[sizeof(EdgeSmem)];
    const int tid = threadIdx.x, wave = tid >> 6, lane = tid & 63;
    const int gtid = blockIdx.x * BLK + tid;
    const int gsz = GRID * BLK;

    // ---------------- P0: init (slot=-1, counters=0, agg_c=0) ----------------
    for (int j = gtid; j < 40960; j += gsz) slot[j] = -1;
    if (gtid < 32) counters[gtid] = 0;
    {
        float4* agg4 = (float4*)agg_c;
        const float4 z = make_float4(0.f, 0.f, 0.f, 0.f);
        for (int j = gtid; j < (MAXU * IN_CH) / 4; j += gsz) agg4[j] = z;
    }
    __threadfence();
    grid.sync();

    // ---------------- P1: flag selected nodes, assign compact slots ----------
    for (int r = gtid; r < NSEL; r += gsz) {
        int node = (r == 0) ? 0 : (r <= N_SAMP ? pos[r - 1] : neg[r - 1 - N_SAMP]);
        int old = atomicCAS(&slot[node], -1, -2);
        if (old == -1) slot[node] = atomicAdd(&counters[1], 1);
    }
    __threadfence();
    grid.sync();

    // ---------------- P2: compact surviving edges ----------------------------
    {
        CmpSmem* cs = (CmpSmem*)smem;
        for (int base = blockIdx.x * BLK; base < N_EDGES; base += gsz) {
            int e = base + tid;
            int d = ei[N_EDGES + e];
            int sl = slot[d];
            bool valid = (sl >= 0);
            unsigned long long m = __ballot(valid);
            int wrank = __popcll(m & ((1ULL << lane) - 1ULL));
            if (lane == 0) cs->woff[wave] = __popcll(m);
            __syncthreads();
            if (tid == 0) {
                int t = 0;
                for (int i = 0; i < 4; ++i) { int c = cs->woff[i]; cs->woff[i] = t; t += c; }
                cs->bbase = atomicAdd(&counters[0], t);
            }
            __syncthreads();
            if (valid) cmp[cs->bbase + cs->woff[wave] + wrank] = make_int4(e, ei[e], sl, 0);
            __syncthreads();
        }
    }
    __threadfence();
    grid.sync();

    // ---------------- P3: edge GEMM + scatter into compact agg_c -------------
    {
        EdgeSmem* es = (EdgeSmem*)smem;
        const int M = counters[0];
        { // stage We once per block
            const float4* s4 = (const float4*)We;
            float4* d4 = (float4*)es->sWe;
            for (int i = tid; i < (EDGE_DIM * IN_CH) / 4; i += BLK) d4[i] = s4[i];
        }
        __syncthreads();
        const float be0 = be[lane], be1 = be[64 + lane];

        for (int b = blockIdx.x * 64; b < M; b += GRID * 64) {
            const int wb = b + wave * 16;
            if (lane < 16) {
                int idx = wb + lane;
                bool v = idx < M;
                int4 c = cmp[v ? idx : 0];
                es->sE[wave][lane] = c.x;
                es->sS[wave][lane] = c.y;
                es->sL[wave][lane] = v ? c.z : -1;
            }
            __syncthreads();
            { // gather 16 attr rows (256 B each, coalesced float4)
                int sub = lane >> 4, q = lane & 15;
#pragma unroll
                for (int p = 0; p < 4; ++p) {
                    int j = p * 4 + sub;
                    int e = es->sE[wave][j];
                    ((float4*)&es->sAttr[wave][j * EDGE_DIM])[q] =
                        ((const float4*)(edge_attr + (size_t)e * EDGE_DIM))[q];
                }
            }
            __syncthreads();

            float acc0[16], acc1[16];
#pragma unroll
            for (int j = 0; j < 16; ++j) { acc0[j] = 0.f; acc1[j] = 0.f; }
            for (int k0 = 0; k0 < EDGE_DIM; k0 += 4) {
                float w0[4], w1[4];
#pragma unroll
                for (int kk = 0; kk < 4; ++kk) {
                    w0[kk] = es->sWe[(k0 + kk) * IN_CH + lane];
                    w1[kk] = es->sWe[(k0 + kk) * IN_CH + 64 + lane];
                }
#pragma unroll
                for (int j = 0; j < 16; ++j) {
                    float4 a = *(const float4*)&es->sAttr[wave][j * EDGE_DIM + k0];
                    acc0[j] += a.x * w0[0] + a.y * w0[1] + a.z * w0[2] + a.w * w0[3];
                    acc1[j] += a.x * w1[0] + a.y * w1[1] + a.z * w1[2] + a.w * w1[3];
                }
            }
#pragma unroll
            for (int j = 0; j < 16; ++j) {
                int sl = es->sL[wave][j];
                if (sl >= 0) {
                    int s = es->sS[wave][j];
                    float m0 = fmaxf(x[(size_t)s * IN_CH + lane] + acc0[j] + be0, 0.f);
                    float m1 = fmaxf(x[(size_t)s * IN_CH + 64 + lane] + acc1[j] + be1, 0.f);
                    atomicAdd(&agg_c[(size_t)sl * IN_CH + lane], m0);
                    atomicAdd(&agg_c[(size_t)sl * IN_CH + 64 + lane], m1);
                }
            }
            __syncthreads();
        }
    }
    __threadfence();
    grid.sync();

    // ---------------- P4: fused MLP on selected rows --------------------------
    {
        MlpSmem* ms = (MlpSmem*)smem;
        for (int tile = blockIdx.x; tile * 16 < NSEL; tile += GRID) {
            const int r0 = tile * 16;
            if (tid < 16) {
                int r = r0 + tid;
                int node = 0;
                if (r < NSEL && r > 0)
                    node = (r <= N_SAMP) ? pos[r - 1] : neg[r - 1 - N_SAMP];
                ms->snode[tid] = node;
                ms->sslot[tid] = slot[node];
            }
            __syncthreads();
            for (int i = tid; i < 16 * (IN_CH / 4); i += BLK) {
                int rr = i >> 5, k4 = i & 31;
                int n = ms->snode[rr], sl = ms->sslot[rr];
                float4 xa = ((const float4*)(x + (size_t)n * IN_CH))[k4];
                float4 ga = ((const float4*)(agg_c + (size_t)sl * IN_CH))[k4];
                ((float4*)ms->sin_[rr])[k4] =
                    make_float4(xa.x + ga.x, xa.y + ga.y, xa.z + ga.z, xa.w + ga.w);
            }
            __syncthreads();

            float acc[16];
#pragma unroll
            for (int rr = 0; rr < 16; ++rr) acc[rr] = 0.f;
            for (int k0 = 0; k0 < IN_CH; k0 += 4) {
                float w[4];
#pragma unroll
                for (int kk = 0; kk < 4; ++kk) w[kk] = W1[(k0 + kk) * HID_CH + tid];
#pragma unroll
                for (int rr = 0; rr < 16; ++rr) {
                    float4 h = *(const float4*)&ms->sin_[rr][k0];
                    acc[rr] += h.x * w[0] + h.y * w[1] + h.z * w[2] + h.w * w[3];
                }
            }
            float bb1 = b1[tid];
#pragma unroll
            for (int rr = 0; rr < 16; ++rr) ms->shid[rr][tid] = fmaxf(acc[rr] + bb1, 0.f);
            __syncthreads();

#pragma unroll
            for (int rr = 0; rr < 16; ++rr) acc[rr] = 0.f;
            for (int k0 = 0; k0 < HID_CH; k0 += 4) {
                float w[4];
#pragma unroll
                for (int kk = 0; kk < 4; ++kk) w[kk] = W2[(k0 + kk) * HID_CH + tid];
#pragma unroll
                for (int rr = 0; rr < 16; ++rr) {
                    float4 h = *(const float4*)&ms->shid[rr][k0];
                    acc[rr] += h.x * w[0] + h.y * w[1] + h.z * w[2] + h.w * w[3];
                }
            }
            float bb2 = b2[tid];
#pragma unroll
            for (int rr = 0; rr < 16; ++rr) {
                int r = r0 + rr;
                if (r < NSEL) emb[(size_t)r * HID_CH + tid] = acc[rr] + bb2;
            }
            __syncthreads();
        }
    }
    __threadfence();
    grid.sync();

    // ---------------- P5: cosine scores vs center (emb row 0) ----------------
    {
        ScSmem* ss = (ScSmem*)smem;
        const float4 c = ((const float4*)emb)[lane];
        float cc = c.x * c.x + c.y * c.y + c.z * c.z + c.w * c.w;
        for (int sb = blockIdx.x; sb < 1024; sb += GRID) {
            const int rid = sb * 4 + wave; // 0..4095
            const float4 v = ((const float4*)(emb + (size_t)(rid + 1) * HID_CH))[lane];
            float vv = v.x * v.x + v.y * v.y + v.z * v.z + v.w * v.w;
            float cv = c.x * v.x + c.y * v.y + c.z * v.z + c.w * v.w;
            float ccr = cc;
#pragma unroll
            for (int off = 32; off; off >>= 1) {
                ccr += __shfl_xor(ccr, off, 64);
                vv += __shfl_xor(vv, off, 64);
                cv += __shfl_xor(cv, off, 64);
            }
            float score = cv / (fmaxf(sqrtf(ccr), 1e-12f) * fmaxf(sqrtf(vv), 1e-12f));
            if (lane == 0) ss->wsum[wave] = score;
            __syncthreads();
            if (tid == 0)
                partial[sb] = ss->wsum[0] + ss->wsum[1] + ss->wsum[2] + ss->wsum[3];
            __syncthreads();
        }
    }
    __threadfence();
    grid.sync();

    // ---------------- P6: final loss (block 0, wave 0) ------------------------
    if (blockIdx.x == 0 && tid < 64) {
        const float4 c = ((const float4*)emb)[lane];
        const float4 t = ((const float4*)thrn)[lane];
        float cc = c.x * c.x + c.y * c.y + c.z * c.z + c.w * c.w;
        float tt = t.x * t.x + t.y * t.y + t.z * t.z + t.w * t.w;
        float ct = c.x * t.x + c.y * t.y + c.z * t.z + c.w * t.w;
        float ps = 0.f, ns = 0.f;
#pragma unroll
        for (int i = 0; i < 8; ++i) ps += partial[lane + 64 * i];
#pragma unroll
        for (int i = 0; i < 8; ++i) ns += partial[512 + lane + 64 * i];
#pragma unroll
        for (int off = 32; off; off >>= 1) {
            cc += __shfl_xor(cc, off, 64);
            tt += __shfl_xor(tt, off, 64);
            ct += __shfl_xor(ct, off, 64);
            ps += __shfl_xor(ps, off, 64);
            ns += __shfl_xor(ns, off, 64);
        }
        if (lane == 0) {
            float thr = ct / (fmaxf(sqrtf(cc), 1e-12f) * fmaxf(sqrtf(tt), 1e-12f));
            float pm = ps / (float)N_SAMP;
            float nm = ns / (float)N_SAMP;
            float s1 = 1.f / (1.f + expf(-(pm - thr)));
            float s2 = 1.f / (1.f + expf(-(thr - nm)));
            s1 = fmaxf(s1, 1e-12f);
            s2 = fmaxf(s2, 1e-12f);
            out[0] = -(logf(s1) + logf(s2));
        }
    }
}

extern "C" void kernel_launch(void* const* d_in, const int* in_sizes, int n_in,
                              void* d_out, int out_size, void* d_ws, size_t ws_size,
                              hipStream_t stream)
{
    const float* x         = (const float*)d_in[0];
    const int*   ei        = (const int*)d_in[1];
    const float* edge_attr = (const float*)d_in[2];
    const int*   pos       = (const int*)d_in[3];
    const int*   neg       = (const int*)d_in[4];
    const float* We        = (const float*)d_in[5];
    const float* be        = (const float*)d_in[6];
    const float* W1        = (const float*)d_in[7];
    const float* b1        = (const float*)d_in[8];
    const float* W2        = (const float*)d_in[9];
    const float* b2        = (const float*)d_in[10];
    const float* thrn      = (const float*)d_in[11];
    float* out = (float*)d_out;

    int* slot     = (int*)d_ws;                  // 40960 ints
    int* counters = slot + 40960;                // 32
    int4* cmp     = (int4*)(counters + 32);      // 640000 int4 (offset 163968, 16B-aligned)
    float* agg_c  = (float*)(cmp + N_EDGES);     // 4097*128 (pad 524800)
    float* emb    = agg_c + 524800;              // 4097*256 (pad 1048832)
    float* partial = emb + 1048832;              // 1024

    void* args[] = {
        (void*)&x, (void*)&ei, (void*)&edge_attr, (void*)&pos, (void*)&neg,
        (void*)&We, (void*)&be, (void*)&W1, (void*)&b1, (void*)&W2, (void*)&b2,
        (void*)&thrn, (void*)&slot, (void*)&counters, (void*)&cmp, (void*)&agg_c,
        (void*)&emb, (void*)&partial, (void*)&out};
    hipLaunchCooperativeKernel((void*)mega_kernel, dim3(GRID), dim3(BLK),
                               args, 0, stream);
}

// Round 5
// 400.402 us; speedup vs baseline: 2.2955x; 2.2955x over previous
//
#include <hip/hip_runtime.h>
#include <math.h>

#define N_NODES 40000
#define N_EDGES 640000
#define IN_CH 128
#define HID_CH 256
#define EDGE_DIM 64
#define N_SAMP 2048
#define NSEL (1 + 2 * N_SAMP) /* 4097 selected rows */
#define MAXU 4097
#define QCAP 512 /* LDS edge queue capacity (power of 2); max in-flight 63+256=319 */

// ---------------------------------------------------------------------------
// Init: slot=-1, counters=0 (ints; [2],[3] aliased as float sums), agg_c=0.
// ---------------------------------------------------------------------------
__global__ __launch_bounds__(256) void init_kernel(
    int* __restrict__ slot, int* __restrict__ counters, float4* __restrict__ agg4)
{
    const int i = blockIdx.x * 256 + threadIdx.x;
    const int n = gridDim.x * 256;
    for (int j = i; j < 40960; j += n) slot[j] = -1;
    if (i < 32) counters[i] = 0;
    const float4 z = make_float4(0.f, 0.f, 0.f, 0.f);
    for (int j = i; j < (MAXU * IN_CH) / 4; j += n) agg4[j] = z;
}

// ---------------------------------------------------------------------------
// Flag selected nodes, assign dense compact slots (CAS dedup).
// ---------------------------------------------------------------------------
__global__ __launch_bounds__(256) void flag_kernel(
    const int* __restrict__ pos, const int* __restrict__ neg,
    int* __restrict__ slot, int* __restrict__ counters)
{
    int r = blockIdx.x * 256 + threadIdx.x;
    if (r >= NSEL) return;
    int node = (r == 0) ? 0 : (r <= N_SAMP ? pos[r - 1] : neg[r - 1 - N_SAMP]);
    int old = atomicCAS(&slot[node], -1, -2);
    if (old == -1) slot[node] = atomicAdd(&counters[1], 1);
}

// ---------------------------------------------------------------------------
// Fused edge kernel: stream 1024 edges/block; ballot-compact survivors into
// an LDS ring queue; pop 64-edge GEMM tiles (16/wave) as it fills; drain a
// masked tile at the end. edge_emb = attr@We + be; msg = relu(x[src]+emb);
// atomicAdd into compact agg_c (2 MB, L2-resident).
// ---------------------------------------------------------------------------
struct EdgeSmem {
    float sWe[EDGE_DIM * IN_CH];   // 32 KB
    float sAttr[4][16 * EDGE_DIM]; // 16 KB
    int qE[QCAP], qL[QCAP];        // 4 KB
    int sE[4][16], sS[4][16], sL[4][16];
    int sWc[4], sQbase, sHead, sTail;
};

__device__ __forceinline__ void process_tile(
    EdgeSmem* es, int base, int rem,
    const float* __restrict__ x, const int* __restrict__ ei,
    const float* __restrict__ edge_attr, float be0, float be1,
    float* __restrict__ agg_c, int wave, int lane)
{
    if (lane < 16) {
        int p = wave * 16 + lane;
        bool v = p < rem;
        int qi = (base + p) & (QCAP - 1);
        int e = v ? es->qE[qi] : 0;
        es->sE[wave][lane] = e;
        es->sS[wave][lane] = v ? ei[e] : 0;
        es->sL[wave][lane] = v ? es->qL[qi] : -1;
    }
    __syncthreads();
    { // stage 16 attr rows per wave (invalid -> row 0, harmless)
        int sub = lane >> 4, q = lane & 15;
#pragma unroll
        for (int p = 0; p < 4; ++p) {
            int j = p * 4 + sub;
            int e = es->sE[wave][j];
            ((float4*)&es->sAttr[wave][j * EDGE_DIM])[q] =
                ((const float4*)(edge_attr + (size_t)e * EDGE_DIM))[q];
        }
    }
    __syncthreads();

    float acc0[16], acc1[16];
#pragma unroll
    for (int j = 0; j < 16; ++j) { acc0[j] = 0.f; acc1[j] = 0.f; }
    for (int k0 = 0; k0 < EDGE_DIM; k0 += 4) {
        float w0[4], w1[4];
#pragma unroll
        for (int kk = 0; kk < 4; ++kk) {
            w0[kk] = es->sWe[(k0 + kk) * IN_CH + lane];
            w1[kk] = es->sWe[(k0 + kk) * IN_CH + 64 + lane];
        }
#pragma unroll
        for (int j = 0; j < 16; ++j) {
            float4 a = *(const float4*)&es->sAttr[wave][j * EDGE_DIM + k0];
            acc0[j] += a.x * w0[0] + a.y * w0[1] + a.z * w0[2] + a.w * w0[3];
            acc1[j] += a.x * w1[0] + a.y * w1[1] + a.z * w1[2] + a.w * w1[3];
        }
    }
#pragma unroll
    for (int j = 0; j < 16; ++j) {
        int sl = es->sL[wave][j];
        if (sl >= 0) {
            int s = es->sS[wave][j];
            float m0 = fmaxf(x[(size_t)s * IN_CH + lane] + acc0[j] + be0, 0.f);
            float m1 = fmaxf(x[(size_t)s * IN_CH + 64 + lane] + acc1[j] + be1, 0.f);
            atomicAdd(&agg_c[(size_t)sl * IN_CH + lane], m0);
            atomicAdd(&agg_c[(size_t)sl * IN_CH + 64 + lane], m1);
        }
    }
}

__global__ __launch_bounds__(256) void edge_kernel(
    const float* __restrict__ x, const int* __restrict__ ei,
    const float* __restrict__ edge_attr, const float* __restrict__ We,
    const float* __restrict__ be, const int* __restrict__ slot,
    float* __restrict__ agg_c)
{
    __shared__ EdgeSmem es;
    const int tid = threadIdx.x, wave = tid >> 6, lane = tid & 63;

    { // stage We once per block
        const float4* s4 = (const float4*)We;
        float4* d4 = (float4*)es.sWe;
        for (int i = tid; i < (EDGE_DIM * IN_CH) / 4; i += 256) d4[i] = s4[i];
    }
    if (tid == 0) { es.sHead = 0; es.sTail = 0; }
    __syncthreads();
    const float be0 = be[lane], be1 = be[64 + lane];

    // 625 blocks x 1024 edges = 640000 exactly; 4 chunks of 256
    const int base0 = blockIdx.x * 1024;
#pragma unroll 1
    for (int c = 0; c < 4; ++c) {
        int e = base0 + c * 256 + tid;
        int d = ei[N_EDGES + e];
        int sl = slot[d];
        bool valid = (sl >= 0);
        unsigned long long m = __ballot(valid);
        int wrank = __popcll(m & ((1ULL << lane) - 1ULL));
        if (lane == 0) es.sWc[wave] = __popcll(m);
        __syncthreads();
        if (tid == 0) {
            int t = 0;
            for (int i = 0; i < 4; ++i) { int cc = es.sWc[i]; es.sWc[i] = t; t += cc; }
            es.sQbase = es.sTail;
            es.sTail = es.sQbase + t;
        }
        __syncthreads();
        if (valid) {
            int idx = (es.sQbase + es.sWc[wave] + wrank) & (QCAP - 1);
            es.qE[idx] = e;
            es.qL[idx] = sl;
        }
        // pop full tiles
        while (true) {
            __syncthreads();
            int h = es.sHead, t = es.sTail;
            if (t - h < 64) break;
            process_tile(&es, h, 64, x, ei, edge_attr, be0, be1, agg_c, wave, lane);
            if (tid == 0) es.sHead = h + 64;
        }
    }
    // drain remainder (masked tile)
    __syncthreads();
    int h = es.sHead, t = es.sTail;
    if (t - h > 0)
        process_tile(&es, h, t - h, x, ei, edge_attr, be0, be1, agg_c, wave, lane);
}

// ---------------------------------------------------------------------------
// Fused MLP + score: each block computes 16 sample rows + the center row (17),
// normalizes in LDS, scores vs center, atomically accumulates pos/neg sums.
// Block 0 writes the center embedding for the loss kernel.
// ---------------------------------------------------------------------------
struct MlpSmem {
    float sin_[17][IN_CH];  // 8.5 KB
    float shid[17][HID_CH]; // 17 KB
    float semb[17][HID_CH]; // 17 KB
    int snode[17], sslot[17];
    float wpos[4], wneg[4];
};

__global__ __launch_bounds__(256) void mlpscore_kernel(
    const float* __restrict__ x, const float* __restrict__ agg_c,
    const int* __restrict__ slot, const int* __restrict__ pos,
    const int* __restrict__ neg, const float* __restrict__ W1,
    const float* __restrict__ b1, const float* __restrict__ W2,
    const float* __restrict__ b2, float* __restrict__ fsum,
    float* __restrict__ embC)
{
    __shared__ MlpSmem ms;
    const int tid = threadIdx.x, wave = tid >> 6, lane = tid & 63;
    const int r0 = blockIdx.x * 16;
    if (tid < 17) {
        int node = 0;
        if (tid < 16) {
            int r = r0 + tid;
            if (r < NSEL && r > 0)
                node = (r <= N_SAMP) ? pos[r - 1] : neg[r - 1 - N_SAMP];
        } // tid==16 -> center node 0
        ms.snode[tid] = node;
        ms.sslot[tid] = slot[node];
    }
    __syncthreads();
    for (int i = tid; i < 17 * (IN_CH / 4); i += 256) {
        int rr = i / 32, k4 = i % 32;
        int n = ms.snode[rr], sl = ms.sslot[rr];
        float4 xa = ((const float4*)(x + (size_t)n * IN_CH))[k4];
        float4 ga = ((const float4*)(agg_c + (size_t)sl * IN_CH))[k4];
        ((float4*)ms.sin_[rr])[k4] =
            make_float4(xa.x + ga.x, xa.y + ga.y, xa.z + ga.z, xa.w + ga.w);
    }
    __syncthreads();

    float acc[17];
#pragma unroll
    for (int rr = 0; rr < 17; ++rr) acc[rr] = 0.f;
    for (int k0 = 0; k0 < IN_CH; k0 += 4) {
        float w[4];
#pragma unroll
        for (int kk = 0; kk < 4; ++kk) w[kk] = W1[(k0 + kk) * HID_CH + tid];
#pragma unroll
        for (int rr = 0; rr < 17; ++rr) {
            float4 h = *(const float4*)&ms.sin_[rr][k0];
            acc[rr] += h.x * w[0] + h.y * w[1] + h.z * w[2] + h.w * w[3];
        }
    }
    float bb1 = b1[tid];
#pragma unroll
    for (int rr = 0; rr < 17; ++rr) ms.shid[rr][tid] = fmaxf(acc[rr] + bb1, 0.f);
    __syncthreads();

#pragma unroll
    for (int rr = 0; rr < 17; ++rr) acc[rr] = 0.f;
    for (int k0 = 0; k0 < HID_CH; k0 += 4) {
        float w[4];
#pragma unroll
        for (int kk = 0; kk < 4; ++kk) w[kk] = W2[(k0 + kk) * HID_CH + tid];
#pragma unroll
        for (int rr = 0; rr < 17; ++rr) {
            float4 h = *(const float4*)&ms.shid[rr][k0];
            acc[rr] += h.x * w[0] + h.y * w[1] + h.z * w[2] + h.w * w[3];
        }
    }
    float bb2 = b2[tid];
#pragma unroll
    for (int rr = 0; rr < 17; ++rr) ms.semb[rr][tid] = acc[rr] + bb2;
    __syncthreads();

    // center fragment (per-wave, lanes hold float4 of center row)
    const float4 c4 = ((const float4*)ms.semb[16])[lane];
    float css = c4.x * c4.x + c4.y * c4.y + c4.z * c4.z + c4.w * c4.w;
#pragma unroll
    for (int off = 32; off; off >>= 1) css += __shfl_xor(css, off, 64);
    const float cn = fmaxf(sqrtf(css), 1e-12f);

    float psum = 0.f, nsum = 0.f;
    for (int rr = wave; rr < 16; rr += 4) {
        int r = r0 + rr;
        if (r < 1 || r >= NSEL) continue;
        const float4 v = ((const float4*)ms.semb[rr])[lane];
        float vv = v.x * v.x + v.y * v.y + v.z * v.z + v.w * v.w;
        float cv = c4.x * v.x + c4.y * v.y + c4.z * v.z + c4.w * v.w;
#pragma unroll
        for (int off = 32; off; off >>= 1) {
            vv += __shfl_xor(vv, off, 64);
            cv += __shfl_xor(cv, off, 64);
        }
        float score = cv / (cn * fmaxf(sqrtf(vv), 1e-12f));
        if (r <= N_SAMP) psum += score; else nsum += score;
    }
    if (lane == 0) { ms.wpos[wave] = psum; ms.wneg[wave] = nsum; }
    __syncthreads();
    if (tid == 0) {
        atomicAdd(&fsum[0], ms.wpos[0] + ms.wpos[1] + ms.wpos[2] + ms.wpos[3]);
        atomicAdd(&fsum[1], ms.wneg[0] + ms.wneg[1] + ms.wneg[2] + ms.wneg[3]);
    }
    if (blockIdx.x == 0) embC[tid] = ms.semb[16][tid]; // deterministic center row
}

// ---------------------------------------------------------------------------
// Final loss: one block. thr = cos(center, thrn); BCE from accumulated sums.
// ---------------------------------------------------------------------------
__global__ __launch_bounds__(256) void loss_kernel(
    const float* __restrict__ embC, const float* __restrict__ thrn,
    const float* __restrict__ fsum, float* __restrict__ out)
{
    __shared__ float rcc[4], rtt[4], rct[4];
    const int tid = threadIdx.x, wave = tid >> 6, lane = tid & 63;
    float c = embC[tid], t = thrn[tid];
    float cc = c * c, tt = t * t, ct = c * t;
#pragma unroll
    for (int off = 32; off; off >>= 1) {
        cc += __shfl_xor(cc, off, 64);
        tt += __shfl_xor(tt, off, 64);
        ct += __shfl_xor(ct, off, 64);
    }
    if (lane == 0) { rcc[wave] = cc; rtt[wave] = tt; rct[wave] = ct; }
    __syncthreads();
    if (tid == 0) {
        float scc = rcc[0] + rcc[1] + rcc[2] + rcc[3];
        float stt = rtt[0] + rtt[1] + rtt[2] + rtt[3];
        float sct = rct[0] + rct[1] + rct[2] + rct[3];
        float thr = sct / (fmaxf(sqrtf(scc), 1e-12f) * fmaxf(sqrtf(stt), 1e-12f));
        float pm = fsum[0] / (float)N_SAMP;
        float nm = fsum[1] / (float)N_SAMP;
        float s1 = 1.f / (1.f + expf(-(pm - thr)));
        float s2 = 1.f / (1.f + expf(-(thr - nm)));
        s1 = fmaxf(s1, 1e-12f);
        s2 = fmaxf(s2, 1e-12f);
        out[0] = -(logf(s1) + logf(s2));
    }
}

extern "C" void kernel_launch(void* const* d_in, const int* in_sizes, int n_in,
                              void* d_out, int out_size, void* d_ws, size_t ws_size,
                              hipStream_t stream)
{
    const float* x         = (const float*)d_in[0];
    const int*   ei        = (const int*)d_in[1];
    const float* edge_attr = (const float*)d_in[2];
    const int*   pos       = (const int*)d_in[3];
    const int*   neg       = (const int*)d_in[4];
    const float* We        = (const float*)d_in[5];
    const float* be        = (const float*)d_in[6];
    const float* W1        = (const float*)d_in[7];
    const float* b1        = (const float*)d_in[8];
    const float* W2        = (const float*)d_in[9];
    const float* b2        = (const float*)d_in[10];
    const float* thrn      = (const float*)d_in[11];
    float* out = (float*)d_out;

    int* slot     = (int*)d_ws;              // 40960 ints
    int* counters = slot + 40960;            // 32 ints ([2],[3] alias float sums)
    float* fsum   = (float*)(counters + 2);  // counters[2],[3] as float
    float* agg_c  = (float*)(counters + 32); // 4097*128 (pad 524800)
    float* embC   = agg_c + 524800;          // 256

    init_kernel<<<256, 256, 0, stream>>>(slot, counters, (float4*)agg_c);
    flag_kernel<<<(NSEL + 255) / 256, 256, 0, stream>>>(pos, neg, slot, counters);
    edge_kernel<<<N_EDGES / 1024, 256, 0, stream>>>(x, ei, edge_attr, We, be, slot, agg_c);
    mlpscore_kernel<<<(NSEL + 15) / 16, 256, 0, stream>>>(
        x, agg_c, slot, pos, neg, W1, b1, W2, b2, fsum, embC);
    loss_kernel<<<1, 256, 0, stream>>>(embC, thrn, fsum, out);
}

// Round 6
// 380.541 us; speedup vs baseline: 2.4154x; 1.0522x over previous
//
#include <hip/hip_runtime.h>
#include <math.h>

#define N_NODES 40000
#define N_EDGES 640000
#define IN_CH 128
#define HID_CH 256
#define EDGE_DIM 64
#define N_SAMP 2048
#define NSEL (1 + 2 * N_SAMP) /* 4097 selected rows */
#define MAXU 4097
#define EGRID 768 /* edge kernel blocks; 3072 waves own slots round-robin */

// ---------------------------------------------------------------------------
// Init: slot=-1, counters=0 ([2],[3] alias float score sums), hist=0.
// agg_c needs no init: every slot < U is stored exactly once by its owner.
// ---------------------------------------------------------------------------
__global__ __launch_bounds__(256) void init_kernel(
    int* __restrict__ slot, int* __restrict__ counters, int* __restrict__ hist)
{
    const int i = blockIdx.x * 256 + threadIdx.x; // grid 160 -> 40960 threads
    slot[i] = -1;
    if (i < 32) counters[i] = 0;
    if (i < 5120) hist[i] = 0;
}

// ---------------------------------------------------------------------------
// Flag selected nodes, assign dense compact slots (CAS dedup).
// ---------------------------------------------------------------------------
__global__ __launch_bounds__(256) void flag_kernel(
    const int* __restrict__ pos, const int* __restrict__ neg,
    int* __restrict__ slot, int* __restrict__ counters)
{
    int r = blockIdx.x * 256 + threadIdx.x;
    if (r >= NSEL) return;
    int node = (r == 0) ? 0 : (r <= N_SAMP ? pos[r - 1] : neg[r - 1 - N_SAMP]);
    int old = atomicCAS(&slot[node], -1, -2);
    if (old == -1) slot[node] = atomicAdd(&counters[1], 1);
}

// ---------------------------------------------------------------------------
// Histogram surviving edges per slot (int atomics on 16 KB array — cheap).
// ---------------------------------------------------------------------------
__global__ __launch_bounds__(256) void hist_kernel(
    const int* __restrict__ ei, const int* __restrict__ slot,
    int* __restrict__ hist)
{
    int e = blockIdx.x * 256 + threadIdx.x;
    int sl = slot[ei[N_EDGES + e]];
    if (sl >= 0) atomicAdd(&hist[sl], 1);
}

// ---------------------------------------------------------------------------
// Exclusive scan of hist -> cursor (mutable) and start (stable CSR offsets).
// One block, 1024 threads x 5 entries = 5120 >= 4098.
// ---------------------------------------------------------------------------
__global__ __launch_bounds__(1024) void scan_kernel(
    const int* __restrict__ hist, int* __restrict__ cursor,
    int* __restrict__ start)
{
    __shared__ int tmp[1024];
    const int t = threadIdx.x;
    int v[5]; int s = 0;
#pragma unroll
    for (int i = 0; i < 5; ++i) { v[i] = hist[t * 5 + i]; s += v[i]; }
    tmp[t] = s;
    __syncthreads();
    for (int d = 1; d < 1024; d <<= 1) {
        int a = (t >= d) ? tmp[t - d] : 0;
        __syncthreads();
        tmp[t] += a;
        __syncthreads();
    }
    int run = tmp[t] - s;
#pragma unroll
    for (int i = 0; i < 5; ++i) {
        cursor[t * 5 + i] = run;
        start[t * 5 + i] = run;
        run += v[i];
    }
}

// ---------------------------------------------------------------------------
// Scatter surviving edges into slot-sorted order: sorted2[p] = {attr_row, src}.
// ---------------------------------------------------------------------------
__global__ __launch_bounds__(256) void scatter_kernel(
    const int* __restrict__ ei, const int* __restrict__ slot,
    int* __restrict__ cursor, int2* __restrict__ sorted2)
{
    int e = blockIdx.x * 256 + threadIdx.x;
    int sl = slot[ei[N_EDGES + e]];
    if (sl >= 0) {
        int p = atomicAdd(&cursor[sl], 1);
        sorted2[p] = make_int2(e, ei[e]);
    }
}

// ---------------------------------------------------------------------------
// Edge kernel, ZERO fp32 atomics: one wave owns one slot; walks its sorted
// run in 16-edge tiles, accumulates sum(relu(x[src] + attr@We + be)) in
// registers, stores the agg row once. Wave-local (no __syncthreads in the
// divergent loop; __shfl broadcasts edge ids; LDS only for We + attr tile).
// LDS 48.6 KB -> 3 blocks/CU.
// ---------------------------------------------------------------------------
__global__ __launch_bounds__(256) void edge_kernel(
    const float* __restrict__ x, const float* __restrict__ edge_attr,
    const float* __restrict__ We, const float* __restrict__ be,
    const int* __restrict__ counters, const int* __restrict__ start,
    const int2* __restrict__ sorted2, float* __restrict__ agg_c)
{
    __shared__ float sWe[EDGE_DIM * IN_CH];   // 32 KB
    __shared__ float sAttr[4][16 * EDGE_DIM]; // 16 KB
    const int tid = threadIdx.x, wave = tid >> 6, lane = tid & 63;
    const int U = counters[1];

    { // stage We once per block
        const float4* s4 = (const float4*)We;
        float4* d4 = (float4*)sWe;
        for (int i = tid; i < (EDGE_DIM * IN_CH) / 4; i += 256) d4[i] = s4[i];
    }
    __syncthreads();
    const float be0 = be[lane], be1 = be[64 + lane];
    const int sub = lane >> 4, q = lane & 15;

    for (int s = blockIdx.x * 4 + wave; s < U; s += EGRID * 4) {
        const int st = start[s], en = start[s + 1];
        float r0 = 0.f, r1 = 0.f;
        for (int t = st; t < en; t += 16) {
            const int cnt = min(16, en - t); // wave-uniform
            int2 v = make_int2(0, 0);
            if (lane < cnt) v = sorted2[t + lane];
            const int ev = v.x, sv = v.y;
            // stage attr rows (16 lanes per row, 16 B each)
#pragma unroll
            for (int p = 0; p < 4; ++p) {
                int j = p * 4 + sub;
                int e = __shfl(ev, j);
                if (j < cnt)
                    ((float4*)&sAttr[wave][j * EDGE_DIM])[q] =
                        ((const float4*)(edge_attr + (size_t)e * EDGE_DIM))[q];
            }
            // GEMM: all 16 j computed (garbage rows masked at the sum)
            float acc0[16], acc1[16];
#pragma unroll
            for (int j = 0; j < 16; ++j) { acc0[j] = 0.f; acc1[j] = 0.f; }
            for (int k0 = 0; k0 < EDGE_DIM; k0 += 4) {
                float w0[4], w1[4];
#pragma unroll
                for (int kk = 0; kk < 4; ++kk) {
                    w0[kk] = sWe[(k0 + kk) * IN_CH + lane];
                    w1[kk] = sWe[(k0 + kk) * IN_CH + 64 + lane];
                }
#pragma unroll
                for (int j = 0; j < 16; ++j) {
                    float4 a = *(const float4*)&sAttr[wave][j * EDGE_DIM + k0];
                    acc0[j] += a.x * w0[0] + a.y * w0[1] + a.z * w0[2] + a.w * w0[3];
                    acc1[j] += a.x * w1[0] + a.y * w1[1] + a.z * w1[2] + a.w * w1[3];
                }
            }
#pragma unroll
            for (int j = 0; j < 16; ++j) {
                if (j >= cnt) break; // wave-uniform
                int s2 = __shfl(sv, j);
                r0 += fmaxf(x[(size_t)s2 * IN_CH + lane] + acc0[j] + be0, 0.f);
                r1 += fmaxf(x[(size_t)s2 * IN_CH + 64 + lane] + acc1[j] + be1, 0.f);
            }
        }
        agg_c[(size_t)s * IN_CH + lane] = r0;         // plain stores,
        agg_c[(size_t)s * IN_CH + 64 + lane] = r1;    // zero atomics
    }
}

// ---------------------------------------------------------------------------
// Fused MLP + score (unchanged from R5): 16 sample rows + center per block,
// cosine scores vs center, pos/neg sums via 2 atomics/block.
// ---------------------------------------------------------------------------
struct MlpSmem {
    float sin_[17][IN_CH];
    float shid[17][HID_CH];
    float semb[17][HID_CH];
    int snode[17], sslot[17];
    float wpos[4], wneg[4];
};

__global__ __launch_bounds__(256) void mlpscore_kernel(
    const float* __restrict__ x, const float* __restrict__ agg_c,
    const int* __restrict__ slot, const int* __restrict__ pos,
    const int* __restrict__ neg, const float* __restrict__ W1,
    const float* __restrict__ b1, const float* __restrict__ W2,
    const float* __restrict__ b2, float* __restrict__ fsum,
    float* __restrict__ embC)
{
    __shared__ MlpSmem ms;
    const int tid = threadIdx.x, wave = tid >> 6, lane = tid & 63;
    const int r0 = blockIdx.x * 16;
    if (tid < 17) {
        int node = 0;
        if (tid < 16) {
            int r = r0 + tid;
            if (r < NSEL && r > 0)
                node = (r <= N_SAMP) ? pos[r - 1] : neg[r - 1 - N_SAMP];
        }
        ms.snode[tid] = node;
        ms.sslot[tid] = slot[node];
    }
    __syncthreads();
    for (int i = tid; i < 17 * (IN_CH / 4); i += 256) {
        int rr = i / 32, k4 = i % 32;
        int n = ms.snode[rr], sl = ms.sslot[rr];
        float4 xa = ((const float4*)(x + (size_t)n * IN_CH))[k4];
        float4 ga = ((const float4*)(agg_c + (size_t)sl * IN_CH))[k4];
        ((float4*)ms.sin_[rr])[k4] =
            make_float4(xa.x + ga.x, xa.y + ga.y, xa.z + ga.z, xa.w + ga.w);
    }
    __syncthreads();

    float acc[17];
#pragma unroll
    for (int rr = 0; rr < 17; ++rr) acc[rr] = 0.f;
    for (int k0 = 0; k0 < IN_CH; k0 += 4) {
        float w[4];
#pragma unroll
        for (int kk = 0; kk < 4; ++kk) w[kk] = W1[(k0 + kk) * HID_CH + tid];
#pragma unroll
        for (int rr = 0; rr < 17; ++rr) {
            float4 h = *(const float4*)&ms.sin_[rr][k0];
            acc[rr] += h.x * w[0] + h.y * w[1] + h.z * w[2] + h.w * w[3];
        }
    }
    float bb1 = b1[tid];
#pragma unroll
    for (int rr = 0; rr < 17; ++rr) ms.shid[rr][tid] = fmaxf(acc[rr] + bb1, 0.f);
    __syncthreads();

#pragma unroll
    for (int rr = 0; rr < 17; ++rr) acc[rr] = 0.f;
    for (int k0 = 0; k0 < HID_CH; k0 += 4) {
        float w[4];
#pragma unroll
        for (int kk = 0; kk < 4; ++kk) w[kk] = W2[(k0 + kk) * HID_CH + tid];
#pragma unroll
        for (int rr = 0; rr < 17; ++rr) {
            float4 h = *(const float4*)&ms.shid[rr][k0];
            acc[rr] += h.x * w[0] + h.y * w[1] + h.z * w[2] + h.w * w[3];
        }
    }
    float bb2 = b2[tid];
#pragma unroll
    for (int rr = 0; rr < 17; ++rr) ms.semb[rr][tid] = acc[rr] + bb2;
    __syncthreads();

    const float4 c4 = ((const float4*)ms.semb[16])[lane];
    float css = c4.x * c4.x + c4.y * c4.y + c4.z * c4.z + c4.w * c4.w;
#pragma unroll
    for (int off = 32; off; off >>= 1) css += __shfl_xor(css, off, 64);
    const float cn = fmaxf(sqrtf(css), 1e-12f);

    float psum = 0.f, nsum = 0.f;
    for (int rr = wave; rr < 16; rr += 4) {
        int r = r0 + rr;
        if (r < 1 || r >= NSEL) continue;
        const float4 v = ((const float4*)ms.semb[rr])[lane];
        float vv = v.x * v.x + v.y * v.y + v.z * v.z + v.w * v.w;
        float cv = c4.x * v.x + c4.y * v.y + c4.z * v.z + c4.w * v.w;
#pragma unroll
        for (int off = 32; off; off >>= 1) {
            vv += __shfl_xor(vv, off, 64);
            cv += __shfl_xor(cv, off, 64);
        }
        float score = cv / (cn * fmaxf(sqrtf(vv), 1e-12f));
        if (r <= N_SAMP) psum += score; else nsum += score;
    }
    if (lane == 0) { ms.wpos[wave] = psum; ms.wneg[wave] = nsum; }
    __syncthreads();
    if (tid == 0) {
        atomicAdd(&fsum[0], ms.wpos[0] + ms.wpos[1] + ms.wpos[2] + ms.wpos[3]);
        atomicAdd(&fsum[1], ms.wneg[0] + ms.wneg[1] + ms.wneg[2] + ms.wneg[3]);
    }
    if (blockIdx.x == 0) embC[tid] = ms.semb[16][tid];
}

// ---------------------------------------------------------------------------
// Final loss (one block).
// ---------------------------------------------------------------------------
__global__ __launch_bounds__(256) void loss_kernel(
    const float* __restrict__ embC, const float* __restrict__ thrn,
    const float* __restrict__ fsum, float* __restrict__ out)
{
    __shared__ float rcc[4], rtt[4], rct[4];
    const int tid = threadIdx.x, wave = tid >> 6, lane = tid & 63;
    float c = embC[tid], t = thrn[tid];
    float cc = c * c, tt = t * t, ct = c * t;
#pragma unroll
    for (int off = 32; off; off >>= 1) {
        cc += __shfl_xor(cc, off, 64);
        tt += __shfl_xor(tt, off, 64);
        ct += __shfl_xor(ct, off, 64);
    }
    if (lane == 0) { rcc[wave] = cc; rtt[wave] = tt; rct[wave] = ct; }
    __syncthreads();
    if (tid == 0) {
        float scc = rcc[0] + rcc[1] + rcc[2] + rcc[3];
        float stt = rtt[0] + rtt[1] + rtt[2] + rtt[3];
        float sct = rct[0] + rct[1] + rct[2] + rct[3];
        float thr = sct / (fmaxf(sqrtf(scc), 1e-12f) * fmaxf(sqrtf(stt), 1e-12f));
        float pm = fsum[0] / (float)N_SAMP;
        float nm = fsum[1] / (float)N_SAMP;
        float s1 = 1.f / (1.f + expf(-(pm - thr)));
        float s2 = 1.f / (1.f + expf(-(thr - nm)));
        s1 = fmaxf(s1, 1e-12f);
        s2 = fmaxf(s2, 1e-12f);
        out[0] = -(logf(s1) + logf(s2));
    }
}

extern "C" void kernel_launch(void* const* d_in, const int* in_sizes, int n_in,
                              void* d_out, int out_size, void* d_ws, size_t ws_size,
                              hipStream_t stream)
{
    const float* x         = (const float*)d_in[0];
    const int*   ei        = (const int*)d_in[1];
    const float* edge_attr = (const float*)d_in[2];
    const int*   pos       = (const int*)d_in[3];
    const int*   neg       = (const int*)d_in[4];
    const float* We        = (const float*)d_in[5];
    const float* be        = (const float*)d_in[6];
    const float* W1        = (const float*)d_in[7];
    const float* b1        = (const float*)d_in[8];
    const float* W2        = (const float*)d_in[9];
    const float* b2        = (const float*)d_in[10];
    const float* thrn      = (const float*)d_in[11];
    float* out = (float*)d_out;

    int* slot     = (int*)d_ws;              // 40960 ints
    int* counters = slot + 40960;            // 32 ints ([2],[3] alias float sums)
    float* fsum   = (float*)(counters + 2);
    int* hist     = counters + 32;           // 5120
    int* cursor   = hist + 5120;             // 5120
    int* start    = cursor + 5120;           // 5120
    int2* sorted2 = (int2*)(start + 5120);   // 640000 int2 (8B-aligned)
    float* agg_c  = (float*)(sorted2 + N_EDGES); // 4097*128 (pad 524800)
    float* embC   = agg_c + 524800;          // 256

    init_kernel<<<160, 256, 0, stream>>>(slot, counters, hist);
    flag_kernel<<<(NSEL + 255) / 256, 256, 0, stream>>>(pos, neg, slot, counters);
    hist_kernel<<<N_EDGES / 256, 256, 0, stream>>>(ei, slot, hist);
    scan_kernel<<<1, 1024, 0, stream>>>(hist, cursor, start);
    scatter_kernel<<<N_EDGES / 256, 256, 0, stream>>>(ei, slot, cursor, sorted2);
    edge_kernel<<<EGRID, 256, 0, stream>>>(x, edge_attr, We, be, counters,
                                           start, sorted2, agg_c);
    mlpscore_kernel<<<(NSEL + 15) / 16, 256, 0, stream>>>(
        x, agg_c, slot, pos, neg, W1, b1, W2, b2, fsum, embC);
    loss_kernel<<<1, 256, 0, stream>>>(embC, thrn, fsum, out);
}